// Round 6
// baseline (2794.890 us; speedup 1.0000x reference)
//
#include <hip/hip_runtime.h>
#include <math.h>

#define N_NODES 50000
#define N_EDGES 800000
#define HC 64
#define HID 16
#define EDIM 16
#define NGRAPH 2000
#define BN_EPS 1e-5f
#define NBLK 1024
#define NCHUNK 196                       // ceil(50000/256)
#define NTILE ((N_NODES + 31) / 32)      // 1563
#define NGRP (N_NODES / 4)               // 12500

// monotone grid barrier: all NBLK blocks co-resident by construction
__device__ __forceinline__ void grid_bar(int* cnt, int ph) {
    __syncthreads();
    if (threadIdx.x == 0) {
        __hip_atomic_fetch_add(cnt, 1, __ATOMIC_ACQ_REL, __HIP_MEMORY_SCOPE_AGENT);
        int target = NBLK * ph;
        int guard = 0;
        while (__hip_atomic_load(cnt, __ATOMIC_ACQUIRE, __HIP_MEMORY_SCOPE_AGENT) < target) {
            __builtin_amdgcn_s_sleep(4);
            if (++guard > (1 << 20)) break;   // safety valve: fail loud, don't hang
        }
    }
    __syncthreads();
}

__global__ __launch_bounds__(256, 4) void fused_gnn(
    const float* __restrict__ x0, const int* __restrict__ ei,
    const float* __restrict__ edge_attr, const int* __restrict__ batch,
    const float* __restrict__ Wq, const float* __restrict__ bq,
    const float* __restrict__ Wk, const float* __restrict__ bk,
    const float* __restrict__ Wv, const float* __restrict__ bv,
    const float* __restrict__ WeL, const float* __restrict__ Wsk,
    const float* __restrict__ bsk,
    const float* __restrict__ bng, const float* __restrict__ bnb,
    const float* __restrict__ bnm, const float* __restrict__ bnv,
    const float* __restrict__ fc1_w, const float* __restrict__ fc1_b,
    const float* __restrict__ fc2_w, const float* __restrict__ fc2_b,
    float* __restrict__ xA, float* __restrict__ xB,
    float* __restrict__ Qb, float* __restrict__ Sb, float* __restrict__ KVb,
    int* __restrict__ deg, int* __restrict__ row_ptr, int* __restrict__ nxt,
    int* __restrict__ chunk_sum, int* __restrict__ chunk_off,
    int* __restrict__ src_s, float* __restrict__ ea_s,
    int* __restrict__ bar, float* __restrict__ out) {
    __shared__ float smem[32 * HC];      // 8 KB, reused by every phase
    int tid = threadIdx.x;
    int bid = blockIdx.x;
    int ph = 0;

    // ---- P0: zero degree counters ----
    for (int i = bid * 256 + tid; i < N_NODES; i += NBLK * 256) deg[i] = 0;
    grid_bar(bar, ++ph);

    // ---- P1: count in-degree ----
    for (int e = bid * 256 + tid; e < N_EDGES; e += NBLK * 256)
        atomicAdd(&deg[ei[N_EDGES + e]], 1);
    grid_bar(bar, ++ph);

    // ---- P2: per-chunk local sums ----
    if (bid < NCHUNK) {
        int i = bid * 256 + tid;
        int v = (i < N_NODES) ? deg[i] : 0;
        int* s = (int*)smem;
        s[tid] = v;
        __syncthreads();
        for (int d = 128; d > 0; d >>= 1) {
            if (tid < d) s[tid] += s[tid + d];
            __syncthreads();
        }
        if (tid == 0) chunk_sum[bid] = s[0];
    }
    grid_bar(bar, ++ph);

    // ---- P3: scan chunk sums (block 0) ----
    if (bid == 0) {
        int v = (tid < NCHUNK) ? chunk_sum[tid] : 0;
        int* s = (int*)smem;
        s[tid] = v;
        __syncthreads();
        for (int d = 1; d < 256; d <<= 1) {
            int t = (tid >= d) ? s[tid - d] : 0;
            __syncthreads();
            s[tid] += t;
            __syncthreads();
        }
        chunk_off[tid] = s[tid] - v;   // exclusive
    }
    grid_bar(bar, ++ph);

    // ---- P4: per-chunk exclusive scan -> row_ptr / nxt ----
    if (bid < NCHUNK) {
        int i = bid * 256 + tid;
        int v = (i < N_NODES) ? deg[i] : 0;
        int* s = (int*)smem;
        s[tid] = v;
        __syncthreads();
        for (int d = 1; d < 256; d <<= 1) {
            int t = (tid >= d) ? s[tid - d] : 0;
            __syncthreads();
            s[tid] += t;
            __syncthreads();
        }
        int excl = s[tid] - v + chunk_off[bid];
        if (i < N_NODES) { row_ptr[i] = excl; nxt[i] = excl; }
        if (i == 0) row_ptr[N_NODES] = N_EDGES;
    }
    grid_bar(bar, ++ph);

    // ---- P5: scatter edges (src index + edge_attr row) into CSR order ----
    for (int e = bid * 256 + tid; e < N_EDGES; e += NBLK * 256) {
        int d = ei[N_EDGES + e];
        int p = atomicAdd(&nxt[d], 1);
        src_s[p] = ei[e];
        const float4* src = (const float4*)(edge_attr + (size_t)e * EDIM);
        float4 a0 = src[0], a1 = src[1], a2 = src[2], a3 = src[3];
        float4* dst = (float4*)(ea_s + (size_t)p * EDIM);
        dst[0] = a0; dst[1] = a1; dst[2] = a2; dst[3] = a3;
    }

    // ---- layers ----
    for (int l = 0; l < 3; l++) {
        const float* xin = (l == 0) ? x0 : ((l == 1) ? xA : xB);
        float* xout = (l == 1) ? xB : xA;
        const float* lWq = Wq + l * HC * HC; const float* lbq = bq + l * HC;
        const float* lWk = Wk + l * HC * HC; const float* lbk = bk + l * HC;
        const float* lWv = Wv + l * HC * HC; const float* lbv = bv + l * HC;
        const float* lWs = Wsk + l * HC * HC; const float* lbs = bsk + l * HC;
        const float* lWe = WeL + l * EDIM * HC;
        const float* lg = bng + l * HC; const float* lb = bnb + l * HC;
        const float* lm = bnm + l * HC; const float* lv = bnv + l * HC;

        // ---- qkvs: out = xin @ {Wq,Wk,Wv,Ws} + bias ----
        for (int tile = bid; tile < NTILE; tile += NBLK) {
            int n0 = tile * 32;
            __syncthreads();   // protect smem from previous use
            for (int c = tid; c < 32 * HC / 4; c += 256) {
                int row = c >> 4, col4 = c & 15;
                int n = n0 + row;
                float4 v = (n < N_NODES) ? ((const float4*)(xin + (size_t)n * HC))[col4]
                                         : make_float4(0.f, 0.f, 0.f, 0.f);
                ((float4*)&smem[row * HC])[col4] = v;
            }
            __syncthreads();
            int sel = tid >> 6;
            int j = tid & 63;
            const float* W; const float* B; float* Out; int stride; int off;
            if (sel == 0)      { W = lWq; B = lbq; Out = Qb;  stride = HC;     off = 0;  }
            else if (sel == 1) { W = lWk; B = lbk; Out = KVb; stride = 2 * HC; off = 0;  }
            else if (sel == 2) { W = lWv; B = lbv; Out = KVb; stride = 2 * HC; off = HC; }
            else               { W = lWs; B = lbs; Out = Sb;  stride = HC;     off = 0;  }
            float bias = B[j];
            float acc[32];
#pragma unroll
            for (int n = 0; n < 32; n++) acc[n] = bias;
            for (int i4 = 0; i4 < HC / 4; i4++) {
                float w0 = W[(i4 * 4 + 0) * HC + j];
                float w1 = W[(i4 * 4 + 1) * HC + j];
                float w2 = W[(i4 * 4 + 2) * HC + j];
                float w3 = W[(i4 * 4 + 3) * HC + j];
#pragma unroll
                for (int n = 0; n < 32; n++) {
                    float4 xv = ((const float4*)&smem[n * HC])[i4];  // LDS broadcast
                    acc[n] = fmaf(xv.x, w0, acc[n]);
                    acc[n] = fmaf(xv.y, w1, acc[n]);
                    acc[n] = fmaf(xv.z, w2, acc[n]);
                    acc[n] = fmaf(xv.w, w3, acc[n]);
                }
            }
#pragma unroll
            for (int n = 0; n < 32; n++) {
                int node = n0 + n;
                if (node < N_NODES) Out[(size_t)node * stride + off + j] = acc[n];
            }
        }
        grid_bar(bar, ++ph);   // qkvs (and, for l==0, scatter) visible to all

        // ---- attention + skip + BN + ReLU; We read from global (L1-hot, no LDS) ----
        for (int grp = bid; grp < NGRP; grp += NBLK) {
            int node = grp * 4 + (tid >> 6);
            int lane = tid & 63;
            int quarter = lane >> 4;
            int pos = lane & 15;
            int h = pos >> 2;
            int jbase = (pos & 3) * 4;
            int rbeg = row_ptr[node], rend = row_ptr[node + 1];

            float4 q4 = ((const float4*)(Qb + (size_t)node * HC))[pos];
            // qWe[h][jbase+c] = sum_d q[h][d] * We[jbase+c][h*16+d]
            float qwe0 = 0.f, qwe1 = 0.f, qwe2 = 0.f, qwe3 = 0.f;
#pragma unroll
            for (int dd = 0; dd < 4; dd++) {
                int sl = h * 4 + dd;
                float qa = __shfl(q4.x, sl), qb2 = __shfl(q4.y, sl);
                float qc = __shfl(q4.z, sl), qd = __shfl(q4.w, sl);
                float4 w0 = *(const float4*)(lWe + (jbase + 0) * HC + h * 16 + dd * 4);
                float4 w1 = *(const float4*)(lWe + (jbase + 1) * HC + h * 16 + dd * 4);
                float4 w2 = *(const float4*)(lWe + (jbase + 2) * HC + h * 16 + dd * 4);
                float4 w3 = *(const float4*)(lWe + (jbase + 3) * HC + h * 16 + dd * 4);
                qwe0 += qa * w0.x + qb2 * w0.y + qc * w0.z + qd * w0.w;
                qwe1 += qa * w1.x + qb2 * w1.y + qc * w1.z + qd * w1.w;
                qwe2 += qa * w2.x + qb2 * w2.y + qc * w2.z + qd * w2.w;
                qwe3 += qa * w3.x + qb2 * w3.y + qc * w3.z + qd * w3.w;
            }

            float m = -1e30f, den = 0.f;
            float4 acc = make_float4(0.f, 0.f, 0.f, 0.f);
            float4 aea = make_float4(0.f, 0.f, 0.f, 0.f);

            auto proc = [&](float4 k4, float4 ea4) -> float {
                float dot = q4.x * k4.x + q4.y * k4.y + q4.z * k4.z + q4.w * k4.w
                          + qwe0 * ea4.x + qwe1 * ea4.y + qwe2 * ea4.z + qwe3 * ea4.w;
                dot += __shfl_xor(dot, 1);
                dot += __shfl_xor(dot, 2);
                float logit = dot * 0.25f;
                float mn = fmaxf(m, logit);
                float corr = __expf(m - mn);
                float p = __expf(logit - mn);
                den = den * corr + p;
                acc.x *= corr; acc.y *= corr; acc.z *= corr; acc.w *= corr;
                aea.x *= corr; aea.y *= corr; aea.z *= corr; aea.w *= corr;
                m = mn;
                return p;
            };

            int j = rbeg + quarter;
            for (; j + 4 < rend; j += 8) {
                int s0 = src_s[j];
                int s1 = src_s[j + 4];
                const float4* kv0 = (const float4*)(KVb + (size_t)s0 * 2 * HC);
                const float4* kv1 = (const float4*)(KVb + (size_t)s1 * 2 * HC);
                float4 k0 = kv0[pos], v0 = kv0[16 + pos];
                float4 k1 = kv1[pos], v1 = kv1[16 + pos];
                float4 ea0 = ((const float4*)(ea_s + (size_t)j * EDIM))[pos & 3];
                float4 ea1 = ((const float4*)(ea_s + (size_t)(j + 4) * EDIM))[pos & 3];
                float p0 = proc(k0, ea0);
                acc.x = fmaf(p0, v0.x, acc.x); acc.y = fmaf(p0, v0.y, acc.y);
                acc.z = fmaf(p0, v0.z, acc.z); acc.w = fmaf(p0, v0.w, acc.w);
                aea.x = fmaf(p0, ea0.x, aea.x); aea.y = fmaf(p0, ea0.y, aea.y);
                aea.z = fmaf(p0, ea0.z, aea.z); aea.w = fmaf(p0, ea0.w, aea.w);
                float p1 = proc(k1, ea1);
                acc.x = fmaf(p1, v1.x, acc.x); acc.y = fmaf(p1, v1.y, acc.y);
                acc.z = fmaf(p1, v1.z, acc.z); acc.w = fmaf(p1, v1.w, acc.w);
                aea.x = fmaf(p1, ea1.x, aea.x); aea.y = fmaf(p1, ea1.y, aea.y);
                aea.z = fmaf(p1, ea1.z, aea.z); aea.w = fmaf(p1, ea1.w, aea.w);
            }
            if (j < rend) {
                int s0 = src_s[j];
                const float4* kv0 = (const float4*)(KVb + (size_t)s0 * 2 * HC);
                float4 k0 = kv0[pos], v0 = kv0[16 + pos];
                float4 ea0 = ((const float4*)(ea_s + (size_t)j * EDIM))[pos & 3];
                float p0 = proc(k0, ea0);
                acc.x = fmaf(p0, v0.x, acc.x); acc.y = fmaf(p0, v0.y, acc.y);
                acc.z = fmaf(p0, v0.z, acc.z); acc.w = fmaf(p0, v0.w, acc.w);
                aea.x = fmaf(p0, ea0.x, aea.x); aea.y = fmaf(p0, ea0.y, aea.y);
                aea.z = fmaf(p0, ea0.z, aea.z); aea.w = fmaf(p0, ea0.w, aea.w);
            }

#pragma unroll
            for (int off = 16; off <= 32; off <<= 1) {
                float m2 = __shfl_xor(m, off);
                float d2 = __shfl_xor(den, off);
                float ax = __shfl_xor(acc.x, off), ay = __shfl_xor(acc.y, off);
                float az = __shfl_xor(acc.z, off), aw = __shfl_xor(acc.w, off);
                float bx = __shfl_xor(aea.x, off), by = __shfl_xor(aea.y, off);
                float bz = __shfl_xor(aea.z, off), bw = __shfl_xor(aea.w, off);
                float mn = fmaxf(m, m2);
                float c1 = __expf(m - mn), c2 = __expf(m2 - mn);
                den = den * c1 + d2 * c2;
                acc.x = acc.x * c1 + ax * c2; acc.y = acc.y * c1 + ay * c2;
                acc.z = acc.z * c1 + az * c2; acc.w = acc.w * c1 + aw * c2;
                aea.x = aea.x * c1 + bx * c2; aea.y = aea.y * c1 + by * c2;
                aea.z = aea.z * c1 + bz * c2; aea.w = aea.w * c1 + bw * c2;
                m = mn;
            }

            float4 e4 = make_float4(0.f, 0.f, 0.f, 0.f);
#pragma unroll
            for (int jg = 0; jg < 4; jg++) {
                int sl = (lane & 48) | (h * 4 + jg);
                float a0 = __shfl(aea.x, sl), a1 = __shfl(aea.y, sl);
                float a2 = __shfl(aea.z, sl), a3 = __shfl(aea.w, sl);
                float4 w0 = *(const float4*)(lWe + (jg * 4 + 0) * HC + pos * 4);
                float4 w1 = *(const float4*)(lWe + (jg * 4 + 1) * HC + pos * 4);
                float4 w2 = *(const float4*)(lWe + (jg * 4 + 2) * HC + pos * 4);
                float4 w3 = *(const float4*)(lWe + (jg * 4 + 3) * HC + pos * 4);
                e4.x += a0 * w0.x + a1 * w1.x + a2 * w2.x + a3 * w3.x;
                e4.y += a0 * w0.y + a1 * w1.y + a2 * w2.y + a3 * w3.y;
                e4.z += a0 * w0.z + a1 * w1.z + a2 * w2.z + a3 * w3.z;
                e4.w += a0 * w0.w + a1 * w1.w + a2 * w2.w + a3 * w3.w;
            }

            float inv = (rend > rbeg) ? 1.f / den : 0.f;
            float4 sk = ((const float4*)(Sb + (size_t)node * HC))[pos];
            float4 o = make_float4((acc.x + e4.x) * inv + sk.x, (acc.y + e4.y) * inv + sk.y,
                                   (acc.z + e4.z) * inv + sk.z, (acc.w + e4.w) * inv + sk.w);
            float4 g4 = ((const float4*)lg)[pos];
            float4 b4 = ((const float4*)lb)[pos];
            float4 m4 = ((const float4*)lm)[pos];
            float4 vv4 = ((const float4*)lv)[pos];
            o.x = fmaxf((o.x - m4.x) * rsqrtf(vv4.x + BN_EPS) * g4.x + b4.x, 0.f);
            o.y = fmaxf((o.y - m4.y) * rsqrtf(vv4.y + BN_EPS) * g4.y + b4.y, 0.f);
            o.z = fmaxf((o.z - m4.z) * rsqrtf(vv4.z + BN_EPS) * g4.z + b4.z, 0.f);
            o.w = fmaxf((o.w - m4.w) * rsqrtf(vv4.w + BN_EPS) * g4.w + b4.w, 0.f);
            if (quarter == 0) ((float4*)(xout + (size_t)node * HC))[pos] = o;
        }
        grid_bar(bar, ++ph);
    }

    // ---- pool + MLP head: one wave per graph ----
    for (int pg = bid; pg < NGRAPH / 4; pg += NBLK) {
        __syncthreads();   // protect smem
        float* ps = smem;  // 4 x HC
        int q = tid >> 6;
        int lane = tid & 63;
        int g = pg * 4 + q;
        const float* xf = xA;  // layer 2 output
        int lo = 0, hi = N_NODES;
        while (lo < hi) { int mid = (lo + hi) >> 1; if (batch[mid] < g) lo = mid + 1; else hi = mid; }
        int beg = lo;
        lo = 0; hi = N_NODES;
        while (lo < hi) { int mid = (lo + hi) >> 1; if (batch[mid] < g + 1) lo = mid + 1; else hi = mid; }
        int end = lo;
        float s = 0.f;
        for (int i = beg; i < end; i++) s += xf[(size_t)i * HC + lane];
        float invn = (end > beg) ? 1.f / (float)(end - beg) : 1.f;
        ps[q * HC + lane] = s * invn;
        __syncthreads();
        float o = 0.f;
        if (lane < HID) {
            float a = fc1_b[lane];
#pragma unroll
            for (int i = 0; i < HC; i++) a = fmaf(ps[q * HC + i], fc1_w[i * HID + lane], a);
            o = fmaxf(a, 0.f) * fc2_w[lane];
        }
        o += __shfl_xor(o, 1);
        o += __shfl_xor(o, 2);
        o += __shfl_xor(o, 4);
        o += __shfl_xor(o, 8);
        if (lane == 0) out[g] = o + fc2_b[0];
    }
}

extern "C" void kernel_launch(void* const* d_in, const int* in_sizes, int n_in,
                              void* d_out, int out_size, void* d_ws, size_t ws_size,
                              hipStream_t stream) {
    const float* x         = (const float*)d_in[0];
    const int*   ei        = (const int*)d_in[1];
    const float* edge_attr = (const float*)d_in[2];
    const int*   batch     = (const int*)d_in[3];
    const float* Wq = (const float*)d_in[4];  const float* bq = (const float*)d_in[5];
    const float* Wk = (const float*)d_in[6];  const float* bk = (const float*)d_in[7];
    const float* Wv = (const float*)d_in[8];  const float* bv = (const float*)d_in[9];
    const float* We = (const float*)d_in[10];
    const float* Ws = (const float*)d_in[11]; const float* bs = (const float*)d_in[12];
    const float* bng = (const float*)d_in[13]; const float* bnb = (const float*)d_in[14];
    const float* bnm = (const float*)d_in[15]; const float* bnv = (const float*)d_in[16];
    const float* fc1_w = (const float*)d_in[17]; const float* fc1_b = (const float*)d_in[18];
    const float* fc2_w = (const float*)d_in[19]; const float* fc2_b = (const float*)d_in[20];
    float* out = (float*)d_out;

    char* wp = (char*)d_ws;
    auto alloc = [&](size_t b) { void* p = (void*)wp; wp += (b + 255) & ~(size_t)255; return p; };
    float* xA      = (float*)alloc((size_t)N_NODES * HC * 4);
    float* xB      = (float*)alloc((size_t)N_NODES * HC * 4);
    float* Qb      = (float*)alloc((size_t)N_NODES * HC * 4);
    float* Sb      = (float*)alloc((size_t)N_NODES * HC * 4);
    float* KV      = (float*)alloc((size_t)N_NODES * 2 * HC * 4);
    int*   deg     = (int*)alloc((size_t)N_NODES * 4);
    int*   row_ptr = (int*)alloc((size_t)(N_NODES + 1) * 4);
    int*   nxt     = (int*)alloc((size_t)N_NODES * 4);
    int*   csum    = (int*)alloc((size_t)256 * 4);
    int*   coff    = (int*)alloc((size_t)256 * 4);
    int*   src_s   = (int*)alloc((size_t)N_EDGES * 4);
    float* ea_s    = (float*)alloc((size_t)N_EDGES * EDIM * 4);
    int*   bar     = (int*)alloc((size_t)256);

    (void)hipMemsetAsync(bar, 0, 256, stream);

    fused_gnn<<<NBLK, 256, 0, stream>>>(
        x, ei, edge_attr, batch,
        Wq, bq, Wk, bk, Wv, bv, We, Ws, bs,
        bng, bnb, bnm, bnv, fc1_w, fc1_b, fc2_w, fc2_b,
        xA, xB, Qb, Sb, KV,
        deg, row_ptr, nxt, csum, coff, src_s, ea_s, bar, out);
}

// Round 7
// 804.334 us; speedup vs baseline: 3.4748x; 3.4748x over previous
//
#include <hip/hip_runtime.h>
#include <math.h>

#define N_NODES 50000
#define N_EDGES 800000
#define HC 64
#define HID 16
#define EDIM 16
#define NGRAPH 2000
#define BN_EPS 1e-5f
#define QKVS_NODES 32
#define SCAN_NBLK ((N_NODES + 255) / 256)   // 196

// ---------- CSR build ----------
__global__ void count_deg(const int* __restrict__ ei, int* __restrict__ deg) {
    int e = blockIdx.x * blockDim.x + threadIdx.x;
    if (e < N_EDGES) atomicAdd(&deg[ei[N_EDGES + e]], 1);
}

__global__ __launch_bounds__(256) void scan1(const int* __restrict__ deg, int* __restrict__ bsum) {
    __shared__ int s[256];
    int tid = threadIdx.x;
    int i = blockIdx.x * 256 + tid;
    s[tid] = (i < N_NODES) ? deg[i] : 0;
    __syncthreads();
    for (int d = 128; d > 0; d >>= 1) {
        if (tid < d) s[tid] += s[tid + d];
        __syncthreads();
    }
    if (tid == 0) bsum[blockIdx.x] = s[0];
}

__global__ __launch_bounds__(256) void scan2(const int* __restrict__ bsum, int* __restrict__ boff) {
    __shared__ int s[256];
    int tid = threadIdx.x;
    int v = (tid < SCAN_NBLK) ? bsum[tid] : 0;
    s[tid] = v;
    __syncthreads();
    for (int d = 1; d < 256; d <<= 1) {
        int t = (tid >= d) ? s[tid - d] : 0;
        __syncthreads();
        s[tid] += t;
        __syncthreads();
    }
    boff[tid] = s[tid] - v;  // exclusive
}

__global__ __launch_bounds__(256) void scan3(const int* __restrict__ deg, const int* __restrict__ boff,
                                             int* __restrict__ row_ptr, int* __restrict__ nxt) {
    __shared__ int s[256];
    int tid = threadIdx.x;
    int i = blockIdx.x * 256 + tid;
    int v = (i < N_NODES) ? deg[i] : 0;
    s[tid] = v;
    __syncthreads();
    for (int d = 1; d < 256; d <<= 1) {
        int t = (tid >= d) ? s[tid - d] : 0;
        __syncthreads();
        s[tid] += t;
        __syncthreads();
    }
    int excl = s[tid] - v + boff[blockIdx.x];
    if (i < N_NODES) { row_ptr[i] = excl; nxt[i] = excl; }
    if (i == 0) row_ptr[N_NODES] = N_EDGES;
}

// scatter src index AND edge_attr row into CSR order in one pass
__global__ void scatter_edges(const int* __restrict__ ei, int* __restrict__ next_ptr,
                              const float* __restrict__ edge_attr,
                              int* __restrict__ src_s, float* __restrict__ ea_s) {
    int e = blockIdx.x * blockDim.x + threadIdx.x;
    if (e < N_EDGES) {
        int d = ei[N_EDGES + e];
        int p = atomicAdd(&next_ptr[d], 1);
        src_s[p] = ei[e];
        const float4* src = (const float4*)(edge_attr + (size_t)e * EDIM);
        float4 a0 = src[0], a1 = src[1], a2 = src[2], a3 = src[3];
        float4* dst = (float4*)(ea_s + (size_t)p * EDIM);
        dst[0] = a0; dst[1] = a1; dst[2] = a2; dst[3] = a3;
    }
}

// ---------- fused Q/K/V/Skip GEMM (LDS-staged x rows) ----------
__global__ __launch_bounds__(256) void qkvs_kernel(
    const float* __restrict__ x,
    const float* __restrict__ Wq, const float* __restrict__ bq,
    const float* __restrict__ Wk, const float* __restrict__ bk,
    const float* __restrict__ Wv, const float* __restrict__ bv,
    const float* __restrict__ Ws, const float* __restrict__ bs,
    float* __restrict__ Qo, float* __restrict__ KVo, float* __restrict__ So) {
    __shared__ float xs[QKVS_NODES][HC];
    int tid = threadIdx.x;
    int n0 = blockIdx.x * QKVS_NODES;
    for (int c = tid; c < QKVS_NODES * HC / 4; c += 256) {
        int row = c >> 4, col4 = c & 15;
        int n = n0 + row;
        float4 v = (n < N_NODES) ? ((const float4*)(x + (size_t)n * HC))[col4]
                                 : make_float4(0.f, 0.f, 0.f, 0.f);
        ((float4*)&xs[row][0])[col4] = v;
    }
    __syncthreads();
    int sel = tid >> 6;
    int j = tid & 63;
    const float* W; const float* B; float* Out; int stride; int off;
    if (sel == 0)      { W = Wq; B = bq; Out = Qo;  stride = HC;     off = 0;  }
    else if (sel == 1) { W = Wk; B = bk; Out = KVo; stride = 2 * HC; off = 0;  }
    else if (sel == 2) { W = Wv; B = bv; Out = KVo; stride = 2 * HC; off = HC; }
    else               { W = Ws; B = bs; Out = So;  stride = HC;     off = 0;  }
    float bias = B[j];
    float acc[QKVS_NODES];
#pragma unroll
    for (int n = 0; n < QKVS_NODES; n++) acc[n] = bias;
    for (int i4 = 0; i4 < HC / 4; i4++) {
        float w0 = W[(i4 * 4 + 0) * HC + j];
        float w1 = W[(i4 * 4 + 1) * HC + j];
        float w2 = W[(i4 * 4 + 2) * HC + j];
        float w3 = W[(i4 * 4 + 3) * HC + j];
#pragma unroll
        for (int n = 0; n < QKVS_NODES; n++) {
            float4 xv = ((const float4*)&xs[n][0])[i4];  // LDS broadcast
            acc[n] = fmaf(xv.x, w0, acc[n]);
            acc[n] = fmaf(xv.y, w1, acc[n]);
            acc[n] = fmaf(xv.z, w2, acc[n]);
            acc[n] = fmaf(xv.w, w3, acc[n]);
        }
    }
#pragma unroll
    for (int n = 0; n < QKVS_NODES; n++) {
        int node = n0 + n;
        if (node < N_NODES) Out[(size_t)node * stride + off + j] = acc[n];
    }
}

// ---------- attention + skip + BN + ReLU: one wave per node ----------
// Max-free softmax (logits are small by construction: weights*0.05, BN-bounded
// activations -> |logit| << 80, exp() cannot overflow f32). This removes the
// serial dependence through the running max: all edge updates are associative
// sums, so unrolled iterations pipeline freely.
// e_emb factored out of the edge loop:
//   logit edge term:  q.e_emb = (q@We^T).ea   -> qWe precomputed per node
//   value edge term:  sum p*e_emb = (sum p*ea)@We -> applied once in epilogue
__global__ __launch_bounds__(256) void attn_kernel(
    const float* __restrict__ Qf, const float* __restrict__ KV,
    const float* __restrict__ Sf,
    const int* __restrict__ row_ptr, const int* __restrict__ src_s,
    const float* __restrict__ ea_s, const float* __restrict__ We,
    const float* __restrict__ bng, const float* __restrict__ bnb,
    const float* __restrict__ bnm, const float* __restrict__ bnv,
    float* __restrict__ x_out) {
    int tid = threadIdx.x;
    int node = blockIdx.x * 4 + (tid >> 6);   // 12500 blocks exactly
    int lane = tid & 63;
    int quarter = lane >> 4;
    int pos = lane & 15;
    int h = pos >> 2;          // head
    int jbase = (pos & 3) * 4; // this lane's 4 edge-attr indices
    int rbeg = row_ptr[node], rend = row_ptr[node + 1];

    float4 q4 = ((const float4*)(Qf + (size_t)node * HC))[pos];

    // qWe[h][jbase+c] = sum_d q[h][d] * We[jbase+c][h*16+d]  (once per node; We via L1)
    float qwe0 = 0.f, qwe1 = 0.f, qwe2 = 0.f, qwe3 = 0.f;
#pragma unroll
    for (int dd = 0; dd < 4; dd++) {
        int sl = h * 4 + dd;   // lane holding q dims h*16+dd*4 .. +3 (same in all quarters)
        float qa = __shfl(q4.x, sl), qb = __shfl(q4.y, sl);
        float qc = __shfl(q4.z, sl), qd = __shfl(q4.w, sl);
        float4 w0 = *(const float4*)(We + (jbase + 0) * HC + h * 16 + dd * 4);
        float4 w1 = *(const float4*)(We + (jbase + 1) * HC + h * 16 + dd * 4);
        float4 w2 = *(const float4*)(We + (jbase + 2) * HC + h * 16 + dd * 4);
        float4 w3 = *(const float4*)(We + (jbase + 3) * HC + h * 16 + dd * 4);
        qwe0 += qa * w0.x + qb * w0.y + qc * w0.z + qd * w0.w;
        qwe1 += qa * w1.x + qb * w1.y + qc * w1.z + qd * w1.w;
        qwe2 += qa * w2.x + qb * w2.y + qc * w2.z + qd * w2.w;
        qwe3 += qa * w3.x + qb * w3.y + qc * w3.z + qd * w3.w;
    }

    float den = 0.f;
    float4 acc = make_float4(0.f, 0.f, 0.f, 0.f);   // sum p * v
    float4 aea = make_float4(0.f, 0.f, 0.f, 0.f);   // sum p * ea (raw edge attrs)

    auto proc = [&](float4 k4, float4 v4, float4 ea4) {
        float dot = q4.x * k4.x + q4.y * k4.y + q4.z * k4.z + q4.w * k4.w
                  + qwe0 * ea4.x + qwe1 * ea4.y + qwe2 * ea4.z + qwe3 * ea4.w;
        dot += __shfl_xor(dot, 1);
        dot += __shfl_xor(dot, 2);          // 4 lanes of a head hold the head dot
        float p = __expf(dot * 0.25f);      // max-free: logits are small, no overflow
        den += p;
        acc.x = fmaf(p, v4.x, acc.x); acc.y = fmaf(p, v4.y, acc.y);
        acc.z = fmaf(p, v4.z, acc.z); acc.w = fmaf(p, v4.w, acc.w);
        aea.x = fmaf(p, ea4.x, aea.x); aea.y = fmaf(p, ea4.y, aea.y);
        aea.z = fmaf(p, ea4.z, aea.z); aea.w = fmaf(p, ea4.w, aea.w);
    };

    int j = rbeg + quarter;
    for (; j + 4 < rend; j += 8) {
        int s0 = src_s[j];
        int s1 = src_s[j + 4];
        const float4* kv0 = (const float4*)(KV + (size_t)s0 * 2 * HC);
        const float4* kv1 = (const float4*)(KV + (size_t)s1 * 2 * HC);
        float4 k0 = kv0[pos], v0 = kv0[16 + pos];
        float4 k1 = kv1[pos], v1 = kv1[16 + pos];
        float4 ea0 = ((const float4*)(ea_s + (size_t)j * EDIM))[pos & 3];
        float4 ea1 = ((const float4*)(ea_s + (size_t)(j + 4) * EDIM))[pos & 3];
        proc(k0, v0, ea0);
        proc(k1, v1, ea1);
    }
    if (j < rend) {
        int s0 = src_s[j];
        const float4* kv0 = (const float4*)(KV + (size_t)s0 * 2 * HC);
        float4 k0 = kv0[pos], v0 = kv0[16 + pos];
        float4 ea0 = ((const float4*)(ea_s + (size_t)j * EDIM))[pos & 3];
        proc(k0, v0, ea0);
    }

    // merge the 4 quarter-wave partial sums (plain adds — no max bookkeeping)
#pragma unroll
    for (int off = 16; off <= 32; off <<= 1) {
        den   += __shfl_xor(den, off);
        acc.x += __shfl_xor(acc.x, off); acc.y += __shfl_xor(acc.y, off);
        acc.z += __shfl_xor(acc.z, off); acc.w += __shfl_xor(acc.w, off);
        aea.x += __shfl_xor(aea.x, off); aea.y += __shfl_xor(aea.y, off);
        aea.z += __shfl_xor(aea.z, off); aea.w += __shfl_xor(aea.w, off);
    }

    // epilogue: e_contrib[pos*4+c] = sum_j aggEA[h][j] * We[j][pos*4+c]
    float4 e4 = make_float4(0.f, 0.f, 0.f, 0.f);
#pragma unroll
    for (int jg = 0; jg < 4; jg++) {
        int sl = (lane & 48) | (h * 4 + jg);  // lane holding aggEA[h][jg*4 .. +3]
        float a0 = __shfl(aea.x, sl), a1 = __shfl(aea.y, sl);
        float a2 = __shfl(aea.z, sl), a3 = __shfl(aea.w, sl);
        float4 w0 = *(const float4*)(We + (jg * 4 + 0) * HC + pos * 4);
        float4 w1 = *(const float4*)(We + (jg * 4 + 1) * HC + pos * 4);
        float4 w2 = *(const float4*)(We + (jg * 4 + 2) * HC + pos * 4);
        float4 w3 = *(const float4*)(We + (jg * 4 + 3) * HC + pos * 4);
        e4.x += a0 * w0.x + a1 * w1.x + a2 * w2.x + a3 * w3.x;
        e4.y += a0 * w0.y + a1 * w1.y + a2 * w2.y + a3 * w3.y;
        e4.z += a0 * w0.z + a1 * w1.z + a2 * w2.z + a3 * w3.z;
        e4.w += a0 * w0.w + a1 * w1.w + a2 * w2.w + a3 * w3.w;
    }

    float inv = (rend > rbeg) ? 1.f / den : 0.f;
    float4 sk = ((const float4*)(Sf + (size_t)node * HC))[pos];
    float4 o = make_float4((acc.x + e4.x) * inv + sk.x, (acc.y + e4.y) * inv + sk.y,
                           (acc.z + e4.z) * inv + sk.z, (acc.w + e4.w) * inv + sk.w);
    float4 g4 = ((const float4*)bng)[pos];
    float4 b4 = ((const float4*)bnb)[pos];
    float4 m4 = ((const float4*)bnm)[pos];
    float4 vv4 = ((const float4*)bnv)[pos];
    o.x = fmaxf((o.x - m4.x) * rsqrtf(vv4.x + BN_EPS) * g4.x + b4.x, 0.f);
    o.y = fmaxf((o.y - m4.y) * rsqrtf(vv4.y + BN_EPS) * g4.y + b4.y, 0.f);
    o.z = fmaxf((o.z - m4.z) * rsqrtf(vv4.z + BN_EPS) * g4.z + b4.z, 0.f);
    o.w = fmaxf((o.w - m4.w) * rsqrtf(vv4.w + BN_EPS) * g4.w + b4.w, 0.f);
    if (quarter == 0) ((float4*)(x_out + (size_t)node * HC))[pos] = o;
}

// ---------- fused mean-pool + MLP head: one wave per graph ----------
__global__ __launch_bounds__(256) void pool_head(
    const float* __restrict__ x, const int* __restrict__ batch,
    const float* __restrict__ fc1_w, const float* __restrict__ fc1_b,
    const float* __restrict__ fc2_w, const float* __restrict__ fc2_b,
    float* __restrict__ out) {
    __shared__ float ps[4][HC];
    int q = threadIdx.x >> 6;
    int lane = threadIdx.x & 63;
    int g = blockIdx.x * 4 + q;           // 500 * 4 = 2000 exactly
    int lo = 0, hi = N_NODES;
    while (lo < hi) { int mid = (lo + hi) >> 1; if (batch[mid] < g) lo = mid + 1; else hi = mid; }
    int beg = lo;
    lo = 0; hi = N_NODES;
    while (lo < hi) { int mid = (lo + hi) >> 1; if (batch[mid] < g + 1) lo = mid + 1; else hi = mid; }
    int end = lo;
    float s = 0.f;
    for (int i = beg; i < end; i++) s += x[(size_t)i * HC + lane];  // coalesced
    float inv = (end > beg) ? 1.f / (float)(end - beg) : 1.f;
    ps[q][lane] = s * inv;
    __syncthreads();
    float o = 0.f;
    if (lane < HID) {
        float a = fc1_b[lane];
#pragma unroll
        for (int i = 0; i < HC; i++) a = fmaf(ps[q][i], fc1_w[i * HID + lane], a);
        o = fmaxf(a, 0.f) * fc2_w[lane];
    }
    o += __shfl_xor(o, 1);
    o += __shfl_xor(o, 2);
    o += __shfl_xor(o, 4);
    o += __shfl_xor(o, 8);
    if (lane == 0) out[g] = o + fc2_b[0];
}

extern "C" void kernel_launch(void* const* d_in, const int* in_sizes, int n_in,
                              void* d_out, int out_size, void* d_ws, size_t ws_size,
                              hipStream_t stream) {
    const float* x         = (const float*)d_in[0];
    const int*   ei        = (const int*)d_in[1];
    const float* edge_attr = (const float*)d_in[2];
    const int*   batch     = (const int*)d_in[3];
    const float* Wq = (const float*)d_in[4];  const float* bq = (const float*)d_in[5];
    const float* Wk = (const float*)d_in[6];  const float* bk = (const float*)d_in[7];
    const float* Wv = (const float*)d_in[8];  const float* bv = (const float*)d_in[9];
    const float* We = (const float*)d_in[10];
    const float* Ws = (const float*)d_in[11]; const float* bs = (const float*)d_in[12];
    const float* bng = (const float*)d_in[13]; const float* bnb = (const float*)d_in[14];
    const float* bnm = (const float*)d_in[15]; const float* bnv = (const float*)d_in[16];
    const float* fc1_w = (const float*)d_in[17]; const float* fc1_b = (const float*)d_in[18];
    const float* fc2_w = (const float*)d_in[19]; const float* fc2_b = (const float*)d_in[20];
    float* out = (float*)d_out;

    char* wp = (char*)d_ws;
    auto alloc = [&](size_t b) { void* p = (void*)wp; wp += (b + 255) & ~(size_t)255; return p; };
    float* xA      = (float*)alloc((size_t)N_NODES * HC * 4);
    float* xB      = (float*)alloc((size_t)N_NODES * HC * 4);
    float* Qb      = (float*)alloc((size_t)N_NODES * HC * 4);
    float* Sb      = (float*)alloc((size_t)N_NODES * HC * 4);
    float* KV      = (float*)alloc((size_t)N_NODES * 2 * HC * 4);
    int*   deg     = (int*)alloc((size_t)N_NODES * 4);
    int*   row_ptr = (int*)alloc((size_t)(N_NODES + 1) * 4);
    int*   nxt     = (int*)alloc((size_t)N_NODES * 4);
    int*   bsum    = (int*)alloc((size_t)256 * 4);
    int*   boff    = (int*)alloc((size_t)256 * 4);
    int*   src_s   = (int*)alloc((size_t)N_EDGES * 4);
    float* ea_s    = (float*)alloc((size_t)N_EDGES * EDIM * 4);

    (void)hipMemsetAsync(deg, 0, (size_t)N_NODES * 4, stream);

    count_deg<<<(N_EDGES + 255) / 256, 256, 0, stream>>>(ei, deg);
    scan1<<<SCAN_NBLK, 256, 0, stream>>>(deg, bsum);
    scan2<<<1, 256, 0, stream>>>(bsum, boff);
    scan3<<<SCAN_NBLK, 256, 0, stream>>>(deg, boff, row_ptr, nxt);
    scatter_edges<<<(N_EDGES + 255) / 256, 256, 0, stream>>>(ei, nxt, edge_attr, src_s, ea_s);

    const float* xin = x;
    float* bufs[2] = {xA, xB};
    for (int l = 0; l < 3; l++) {
        float* xout = bufs[l & 1];
        qkvs_kernel<<<(N_NODES + QKVS_NODES - 1) / QKVS_NODES, 256, 0, stream>>>(
            xin, Wq + l * HC * HC, bq + l * HC, Wk + l * HC * HC, bk + l * HC,
            Wv + l * HC * HC, bv + l * HC, Ws + l * HC * HC, bs + l * HC,
            Qb, KV, Sb);
        attn_kernel<<<N_NODES / 4, 256, 0, stream>>>(
            Qb, KV, Sb, row_ptr, src_s, ea_s, We + l * EDIM * HC,
            bng + l * HC, bnb + l * HC, bnm + l * HC, bnv + l * HC, xout);
        xin = xout;
    }
    pool_head<<<NGRAPH / 4, 256, 0, stream>>>(xin, batch, fc1_w, fc1_b, fc2_w, fc2_b, out);
}

// Round 8
// 607.711 us; speedup vs baseline: 4.5990x; 1.3235x over previous
//
#include <hip/hip_runtime.h>
#include <math.h>

#define N_NODES 50000
#define N_EDGES 800000
#define HC 64
#define HID 16
#define EDIM 16
#define NGRAPH 2000
#define BN_EPS 1e-5f
#define QKVS_NODES 32
#define SCAN_NBLK ((N_NODES + 255) / 256)   // 196

// ---------- CSR build ----------
__global__ void count_deg(const int* __restrict__ ei, int* __restrict__ deg) {
    int e = blockIdx.x * blockDim.x + threadIdx.x;
    if (e < N_EDGES) atomicAdd(&deg[ei[N_EDGES + e]], 1);
}

__global__ __launch_bounds__(256) void scan1(const int* __restrict__ deg, int* __restrict__ bsum) {
    __shared__ int s[256];
    int tid = threadIdx.x;
    int i = blockIdx.x * 256 + tid;
    s[tid] = (i < N_NODES) ? deg[i] : 0;
    __syncthreads();
    for (int d = 128; d > 0; d >>= 1) {
        if (tid < d) s[tid] += s[tid + d];
        __syncthreads();
    }
    if (tid == 0) bsum[blockIdx.x] = s[0];
}

__global__ __launch_bounds__(256) void scan2(const int* __restrict__ bsum, int* __restrict__ boff) {
    __shared__ int s[256];
    int tid = threadIdx.x;
    int v = (tid < SCAN_NBLK) ? bsum[tid] : 0;
    s[tid] = v;
    __syncthreads();
    for (int d = 1; d < 256; d <<= 1) {
        int t = (tid >= d) ? s[tid - d] : 0;
        __syncthreads();
        s[tid] += t;
        __syncthreads();
    }
    boff[tid] = s[tid] - v;  // exclusive
}

__global__ __launch_bounds__(256) void scan3(const int* __restrict__ deg, const int* __restrict__ boff,
                                             int* __restrict__ row_ptr, int* __restrict__ nxt) {
    __shared__ int s[256];
    int tid = threadIdx.x;
    int i = blockIdx.x * 256 + tid;
    int v = (i < N_NODES) ? deg[i] : 0;
    s[tid] = v;
    __syncthreads();
    for (int d = 1; d < 256; d <<= 1) {
        int t = (tid >= d) ? s[tid - d] : 0;
        __syncthreads();
        s[tid] += t;
        __syncthreads();
    }
    int excl = s[tid] - v + boff[blockIdx.x];
    if (i < N_NODES) { row_ptr[i] = excl; nxt[i] = excl; }
    if (i == 0) row_ptr[N_NODES] = N_EDGES;
}

// scatter src index AND edge_attr row into CSR order in one pass
__global__ void scatter_edges(const int* __restrict__ ei, int* __restrict__ next_ptr,
                              const float* __restrict__ edge_attr,
                              int* __restrict__ src_s, float* __restrict__ ea_s) {
    int e = blockIdx.x * blockDim.x + threadIdx.x;
    if (e < N_EDGES) {
        int d = ei[N_EDGES + e];
        int p = atomicAdd(&next_ptr[d], 1);
        src_s[p] = ei[e];
        const float4* src = (const float4*)(edge_attr + (size_t)e * EDIM);
        float4 a0 = src[0], a1 = src[1], a2 = src[2], a3 = src[3];
        float4* dst = (float4*)(ea_s + (size_t)p * EDIM);
        dst[0] = a0; dst[1] = a1; dst[2] = a2; dst[3] = a3;
    }
}

// ---------- fused Q/K/V/Skip GEMM (LDS-staged x rows) + qWe = Q@We^T phase ----------
__global__ __launch_bounds__(256) void qkvs_kernel(
    const float* __restrict__ x,
    const float* __restrict__ Wq, const float* __restrict__ bq,
    const float* __restrict__ Wk, const float* __restrict__ bk,
    const float* __restrict__ Wv, const float* __restrict__ bv,
    const float* __restrict__ Ws, const float* __restrict__ bs,
    const float* __restrict__ We,
    float* __restrict__ Qo, float* __restrict__ KVo, float* __restrict__ So,
    float* __restrict__ qwe_buf) {
    __shared__ float xs[QKVS_NODES][HC];
    int tid = threadIdx.x;
    int n0 = blockIdx.x * QKVS_NODES;
    for (int c = tid; c < QKVS_NODES * HC / 4; c += 256) {
        int row = c >> 4, col4 = c & 15;
        int n = n0 + row;
        float4 v = (n < N_NODES) ? ((const float4*)(x + (size_t)n * HC))[col4]
                                 : make_float4(0.f, 0.f, 0.f, 0.f);
        ((float4*)&xs[row][0])[col4] = v;
    }
    __syncthreads();
    int sel = tid >> 6;
    int j = tid & 63;
    const float* W; const float* B; float* Out; int stride; int off;
    if (sel == 0)      { W = Wq; B = bq; Out = Qo;  stride = HC;     off = 0;  }
    else if (sel == 1) { W = Wk; B = bk; Out = KVo; stride = 2 * HC; off = 0;  }
    else if (sel == 2) { W = Wv; B = bv; Out = KVo; stride = 2 * HC; off = HC; }
    else               { W = Ws; B = bs; Out = So;  stride = HC;     off = 0;  }
    float bias = B[j];
    float acc[QKVS_NODES];
#pragma unroll
    for (int n = 0; n < QKVS_NODES; n++) acc[n] = bias;
    for (int i4 = 0; i4 < HC / 4; i4++) {
        float w0 = W[(i4 * 4 + 0) * HC + j];
        float w1 = W[(i4 * 4 + 1) * HC + j];
        float w2 = W[(i4 * 4 + 2) * HC + j];
        float w3 = W[(i4 * 4 + 3) * HC + j];
#pragma unroll
        for (int n = 0; n < QKVS_NODES; n++) {
            float4 xv = ((const float4*)&xs[n][0])[i4];  // LDS broadcast
            acc[n] = fmaf(xv.x, w0, acc[n]);
            acc[n] = fmaf(xv.y, w1, acc[n]);
            acc[n] = fmaf(xv.z, w2, acc[n]);
            acc[n] = fmaf(xv.w, w3, acc[n]);
        }
    }
#pragma unroll
    for (int n = 0; n < QKVS_NODES; n++) {
        int node = n0 + n;
        if (node < N_NODES) Out[(size_t)node * stride + off + j] = acc[n];
    }

    // ---- phase 2: qWe[node][h*16+jj] = sum_d Q[node][h*16+d] * We[jj][h*16+d] ----
    __syncthreads();                 // xs no longer needed for x
    if (sel == 0) {
#pragma unroll
        for (int n = 0; n < QKVS_NODES; n++) xs[n][j] = acc[n];   // Q tile -> LDS
    }
    __syncthreads();
    {
        int h2 = j >> 4, jj = j & 15;
        float4 wv0 = *(const float4*)(We + jj * HC + h2 * 16 + 0);
        float4 wv1 = *(const float4*)(We + jj * HC + h2 * 16 + 4);
        float4 wv2 = *(const float4*)(We + jj * HC + h2 * 16 + 8);
        float4 wv3 = *(const float4*)(We + jj * HC + h2 * 16 + 12);
#pragma unroll
        for (int n = 0; n < 8; n++) {
            int nn = sel * 8 + n;
            float4 q0 = *(const float4*)&xs[nn][h2 * 16 + 0];
            float4 q1 = *(const float4*)&xs[nn][h2 * 16 + 4];
            float4 q2 = *(const float4*)&xs[nn][h2 * 16 + 8];
            float4 q3 = *(const float4*)&xs[nn][h2 * 16 + 12];
            float s = q0.x * wv0.x + q0.y * wv0.y + q0.z * wv0.z + q0.w * wv0.w
                    + q1.x * wv1.x + q1.y * wv1.y + q1.z * wv1.z + q1.w * wv1.w
                    + q2.x * wv2.x + q2.y * wv2.y + q2.z * wv2.z + q2.w * wv2.w
                    + q3.x * wv3.x + q3.y * wv3.y + q3.z * wv3.z + q3.w * wv3.w;
            int node = n0 + nn;
            if (node < N_NODES) qwe_buf[(size_t)node * HC + j] = s;
        }
    }
}

// ---------- attention + skip + BN + ReLU: TWO nodes per wave (R4 loop semantics) ----------
__global__ __launch_bounds__(256) void attn_kernel(
    const float* __restrict__ Qf, const float* __restrict__ Qwe,
    const float* __restrict__ KV, const float* __restrict__ Sf,
    const int* __restrict__ row_ptr, const int* __restrict__ src_s,
    const float* __restrict__ ea_s, const float* __restrict__ We,
    const float* __restrict__ bng, const float* __restrict__ bnb,
    const float* __restrict__ bnm, const float* __restrict__ bnv,
    float* __restrict__ x_out) {
    __shared__ float we_s[EDIM * HC];  // 4 KB
    int tid = threadIdx.x;
    for (int c = tid; c < EDIM * HC / 4; c += 256)
        ((float4*)we_s)[c] = ((const float4*)We)[c];
    __syncthreads();

    int lane = tid & 63;
    int wave = tid >> 6;
    int half = lane >> 5;                       // which node of the wave's pair
    int node = blockIdx.x * 8 + wave * 2 + half;  // 6250 blocks * 8 = 50000 exactly
    int sub = (lane >> 4) & 1;                  // 2 edge-streams per node
    int pos = lane & 15;
    int h = pos >> 2;
    int rbeg = row_ptr[node], rend = row_ptr[node + 1];

    float4 q4 = ((const float4*)(Qf + (size_t)node * HC))[pos];
    float4 qwe = ((const float4*)(Qwe + (size_t)node * HC))[pos];  // qWe[h][jbase..+3]

    float m = -1e30f, den = 0.f;
    float4 acc = make_float4(0.f, 0.f, 0.f, 0.f);   // sum p * v
    float4 aea = make_float4(0.f, 0.f, 0.f, 0.f);   // sum p * ea

    auto proc = [&](float4 k4, float4 ea4) -> float {
        float dot = q4.x * k4.x + q4.y * k4.y + q4.z * k4.z + q4.w * k4.w
                  + qwe.x * ea4.x + qwe.y * ea4.y + qwe.z * ea4.z + qwe.w * ea4.w;
        dot += __shfl_xor(dot, 1);
        dot += __shfl_xor(dot, 2);
        float logit = dot * 0.25f;
        float mn = fmaxf(m, logit);
        float corr = __expf(m - mn);
        float p = __expf(logit - mn);
        den = den * corr + p;
        acc.x *= corr; acc.y *= corr; acc.z *= corr; acc.w *= corr;
        aea.x *= corr; aea.y *= corr; aea.z *= corr; aea.w *= corr;
        m = mn;
        return p;
    };

    int j = rbeg + sub;
    for (; j + 2 < rend; j += 4) {
        int s0 = src_s[j];
        int s1 = src_s[j + 2];
        const float4* kv0 = (const float4*)(KV + (size_t)s0 * 2 * HC);
        const float4* kv1 = (const float4*)(KV + (size_t)s1 * 2 * HC);
        float4 k0 = kv0[pos], v0 = kv0[16 + pos];
        float4 k1 = kv1[pos], v1 = kv1[16 + pos];
        float4 ea0 = ((const float4*)(ea_s + (size_t)j * EDIM))[pos & 3];
        float4 ea1 = ((const float4*)(ea_s + (size_t)(j + 2) * EDIM))[pos & 3];
        float p0 = proc(k0, ea0);
        acc.x = fmaf(p0, v0.x, acc.x); acc.y = fmaf(p0, v0.y, acc.y);
        acc.z = fmaf(p0, v0.z, acc.z); acc.w = fmaf(p0, v0.w, acc.w);
        aea.x = fmaf(p0, ea0.x, aea.x); aea.y = fmaf(p0, ea0.y, aea.y);
        aea.z = fmaf(p0, ea0.z, aea.z); aea.w = fmaf(p0, ea0.w, aea.w);
        float p1 = proc(k1, ea1);
        acc.x = fmaf(p1, v1.x, acc.x); acc.y = fmaf(p1, v1.y, acc.y);
        acc.z = fmaf(p1, v1.z, acc.z); acc.w = fmaf(p1, v1.w, acc.w);
        aea.x = fmaf(p1, ea1.x, aea.x); aea.y = fmaf(p1, ea1.y, aea.y);
        aea.z = fmaf(p1, ea1.z, aea.z); aea.w = fmaf(p1, ea1.w, aea.w);
    }
    if (j < rend) {
        int s0 = src_s[j];
        const float4* kv0 = (const float4*)(KV + (size_t)s0 * 2 * HC);
        float4 k0 = kv0[pos], v0 = kv0[16 + pos];
        float4 ea0 = ((const float4*)(ea_s + (size_t)j * EDIM))[pos & 3];
        float p0 = proc(k0, ea0);
        acc.x = fmaf(p0, v0.x, acc.x); acc.y = fmaf(p0, v0.y, acc.y);
        acc.z = fmaf(p0, v0.z, acc.z); acc.w = fmaf(p0, v0.w, acc.w);
        aea.x = fmaf(p0, ea0.x, aea.x); aea.y = fmaf(p0, ea0.y, aea.y);
        aea.z = fmaf(p0, ea0.z, aea.z); aea.w = fmaf(p0, ea0.w, aea.w);
    }

    // merge the 2 sub-stream softmax states (within the 32-lane half)
    {
        float m2 = __shfl_xor(m, 16);
        float d2 = __shfl_xor(den, 16);
        float ax = __shfl_xor(acc.x, 16), ay = __shfl_xor(acc.y, 16);
        float az = __shfl_xor(acc.z, 16), aw = __shfl_xor(acc.w, 16);
        float bx = __shfl_xor(aea.x, 16), by = __shfl_xor(aea.y, 16);
        float bz = __shfl_xor(aea.z, 16), bw = __shfl_xor(aea.w, 16);
        float mn = fmaxf(m, m2);
        float c1 = __expf(m - mn), c2 = __expf(m2 - mn);
        den = den * c1 + d2 * c2;
        acc.x = acc.x * c1 + ax * c2; acc.y = acc.y * c1 + ay * c2;
        acc.z = acc.z * c1 + az * c2; acc.w = acc.w * c1 + aw * c2;
        aea.x = aea.x * c1 + bx * c2; aea.y = aea.y * c1 + by * c2;
        aea.z = aea.z * c1 + bz * c2; aea.w = aea.w * c1 + bw * c2;
        m = mn;
    }

    // epilogue: e_contrib[pos*4+c] = sum_j aggEA[h][j] * We[j][pos*4+c]
    float4 e4 = make_float4(0.f, 0.f, 0.f, 0.f);
#pragma unroll
    for (int jg = 0; jg < 4; jg++) {
        int sl = (lane & 32) | (h * 4 + jg);  // lane in this half holding aggEA[h][jg*4..+3]
        float a0 = __shfl(aea.x, sl), a1 = __shfl(aea.y, sl);
        float a2 = __shfl(aea.z, sl), a3 = __shfl(aea.w, sl);
        float4 w0 = *(const float4*)(we_s + (jg * 4 + 0) * HC + pos * 4);
        float4 w1 = *(const float4*)(we_s + (jg * 4 + 1) * HC + pos * 4);
        float4 w2 = *(const float4*)(we_s + (jg * 4 + 2) * HC + pos * 4);
        float4 w3 = *(const float4*)(we_s + (jg * 4 + 3) * HC + pos * 4);
        e4.x += a0 * w0.x + a1 * w1.x + a2 * w2.x + a3 * w3.x;
        e4.y += a0 * w0.y + a1 * w1.y + a2 * w2.y + a3 * w3.y;
        e4.z += a0 * w0.z + a1 * w1.z + a2 * w2.z + a3 * w3.z;
        e4.w += a0 * w0.w + a1 * w1.w + a2 * w2.w + a3 * w3.w;
    }

    float inv = (rend > rbeg) ? 1.f / den : 0.f;
    float4 sk = ((const float4*)(Sf + (size_t)node * HC))[pos];
    float4 o = make_float4((acc.x + e4.x) * inv + sk.x, (acc.y + e4.y) * inv + sk.y,
                           (acc.z + e4.z) * inv + sk.z, (acc.w + e4.w) * inv + sk.w);
    float4 g4 = ((const float4*)bng)[pos];
    float4 b4 = ((const float4*)bnb)[pos];
    float4 m4 = ((const float4*)bnm)[pos];
    float4 vv4 = ((const float4*)bnv)[pos];
    o.x = fmaxf((o.x - m4.x) * rsqrtf(vv4.x + BN_EPS) * g4.x + b4.x, 0.f);
    o.y = fmaxf((o.y - m4.y) * rsqrtf(vv4.y + BN_EPS) * g4.y + b4.y, 0.f);
    o.z = fmaxf((o.z - m4.z) * rsqrtf(vv4.z + BN_EPS) * g4.z + b4.z, 0.f);
    o.w = fmaxf((o.w - m4.w) * rsqrtf(vv4.w + BN_EPS) * g4.w + b4.w, 0.f);
    if (sub == 0) ((float4*)(x_out + (size_t)node * HC))[pos] = o;
}

// ---------- fused mean-pool + MLP head: one wave per graph ----------
__global__ __launch_bounds__(256) void pool_head(
    const float* __restrict__ x, const int* __restrict__ batch,
    const float* __restrict__ fc1_w, const float* __restrict__ fc1_b,
    const float* __restrict__ fc2_w, const float* __restrict__ fc2_b,
    float* __restrict__ out) {
    __shared__ float ps[4][HC];
    int q = threadIdx.x >> 6;
    int lane = threadIdx.x & 63;
    int g = blockIdx.x * 4 + q;           // 500 * 4 = 2000 exactly
    int lo = 0, hi = N_NODES;
    while (lo < hi) { int mid = (lo + hi) >> 1; if (batch[mid] < g) lo = mid + 1; else hi = mid; }
    int beg = lo;
    lo = 0; hi = N_NODES;
    while (lo < hi) { int mid = (lo + hi) >> 1; if (batch[mid] < g + 1) lo = mid + 1; else hi = mid; }
    int end = lo;
    float s = 0.f;
    for (int i = beg; i < end; i++) s += x[(size_t)i * HC + lane];  // coalesced
    float inv = (end > beg) ? 1.f / (float)(end - beg) : 1.f;
    ps[q][lane] = s * inv;
    __syncthreads();
    float o = 0.f;
    if (lane < HID) {
        float a = fc1_b[lane];
#pragma unroll
        for (int i = 0; i < HC; i++) a = fmaf(ps[q][i], fc1_w[i * HID + lane], a);
        o = fmaxf(a, 0.f) * fc2_w[lane];
    }
    o += __shfl_xor(o, 1);
    o += __shfl_xor(o, 2);
    o += __shfl_xor(o, 4);
    o += __shfl_xor(o, 8);
    if (lane == 0) out[g] = o + fc2_b[0];
}

extern "C" void kernel_launch(void* const* d_in, const int* in_sizes, int n_in,
                              void* d_out, int out_size, void* d_ws, size_t ws_size,
                              hipStream_t stream) {
    const float* x         = (const float*)d_in[0];
    const int*   ei        = (const int*)d_in[1];
    const float* edge_attr = (const float*)d_in[2];
    const int*   batch     = (const int*)d_in[3];
    const float* Wq = (const float*)d_in[4];  const float* bq = (const float*)d_in[5];
    const float* Wk = (const float*)d_in[6];  const float* bk = (const float*)d_in[7];
    const float* Wv = (const float*)d_in[8];  const float* bv = (const float*)d_in[9];
    const float* We = (const float*)d_in[10];
    const float* Ws = (const float*)d_in[11]; const float* bs = (const float*)d_in[12];
    const float* bng = (const float*)d_in[13]; const float* bnb = (const float*)d_in[14];
    const float* bnm = (const float*)d_in[15]; const float* bnv = (const float*)d_in[16];
    const float* fc1_w = (const float*)d_in[17]; const float* fc1_b = (const float*)d_in[18];
    const float* fc2_w = (const float*)d_in[19]; const float* fc2_b = (const float*)d_in[20];
    float* out = (float*)d_out;

    char* wp = (char*)d_ws;
    auto alloc = [&](size_t b) { void* p = (void*)wp; wp += (b + 255) & ~(size_t)255; return p; };
    float* xA      = (float*)alloc((size_t)N_NODES * HC * 4);
    float* xB      = (float*)alloc((size_t)N_NODES * HC * 4);
    float* Qb      = (float*)alloc((size_t)N_NODES * HC * 4);
    float* Sb      = (float*)alloc((size_t)N_NODES * HC * 4);
    float* KV      = (float*)alloc((size_t)N_NODES * 2 * HC * 4);
    float* qweb    = (float*)alloc((size_t)N_NODES * HC * 4);
    int*   deg     = (int*)alloc((size_t)N_NODES * 4);
    int*   row_ptr = (int*)alloc((size_t)(N_NODES + 1) * 4);
    int*   nxt     = (int*)alloc((size_t)N_NODES * 4);
    int*   bsum    = (int*)alloc((size_t)256 * 4);
    int*   boff    = (int*)alloc((size_t)256 * 4);
    int*   src_s   = (int*)alloc((size_t)N_EDGES * 4);
    float* ea_s    = (float*)alloc((size_t)N_EDGES * EDIM * 4);

    (void)hipMemsetAsync(deg, 0, (size_t)N_NODES * 4, stream);

    count_deg<<<(N_EDGES + 255) / 256, 256, 0, stream>>>(ei, deg);
    scan1<<<SCAN_NBLK, 256, 0, stream>>>(deg, bsum);
    scan2<<<1, 256, 0, stream>>>(bsum, boff);
    scan3<<<SCAN_NBLK, 256, 0, stream>>>(deg, boff, row_ptr, nxt);
    scatter_edges<<<(N_EDGES + 255) / 256, 256, 0, stream>>>(ei, nxt, edge_attr, src_s, ea_s);

    const float* xin = x;
    float* bufs[2] = {xA, xB};
    for (int l = 0; l < 3; l++) {
        float* xout = bufs[l & 1];
        qkvs_kernel<<<(N_NODES + QKVS_NODES - 1) / QKVS_NODES, 256, 0, stream>>>(
            xin, Wq + l * HC * HC, bq + l * HC, Wk + l * HC * HC, bk + l * HC,
            Wv + l * HC * HC, bv + l * HC, Ws + l * HC * HC, bs + l * HC,
            We + l * EDIM * HC, Qb, KV, Sb, qweb);
        attn_kernel<<<N_NODES / 8, 256, 0, stream>>>(
            Qb, qweb, KV, Sb, row_ptr, src_s, ea_s, We + l * EDIM * HC,
            bng + l * HC, bnb + l * HC, bnm + l * HC, bnv + l * HC, xout);
        xin = xout;
    }
    pool_head<<<NGRAPH / 4, 256, 0, stream>>>(xin, batch, fc1_w, fc1_b, fc2_w, fc2_b, out);
}